// Round 2
// baseline (1233.081 us; speedup 1.0000x reference)
//
#include <hip/hip_runtime.h>

typedef unsigned short u16;

#define DEV static __device__ __forceinline__

DEV float bf2f(u16 v) { unsigned x = ((unsigned)v) << 16; return __uint_as_float(x); }
DEV u16 f2bf(float f) {
    unsigned x = __float_as_uint(f);
    unsigned r = (x + 0x7fffu + ((x >> 16) & 1u)) >> 16;
    return (u16)r;
}

constexpr int BATCH = 2;
constexpr int CH    = 384;
constexpr int HH    = 96;
constexpr int WW    = 96;
constexpr int NTOK  = HH * WW;      // 9216
constexpr int GW    = 48;
constexpr int G     = GW * GW;      // 2304 windows (= M for lo-fi)
constexpr int HEADS = 6;
constexpr float SCALE = 0.17677669529663687f;  // 32^-0.5

DEV void unpack8(uint4 u, float* f) {
    unsigned a0 = u.x, a1 = u.y, a2 = u.z, a3 = u.w;
    f[0] = bf2f((u16)(a0 & 0xffffu)); f[1] = bf2f((u16)(a0 >> 16));
    f[2] = bf2f((u16)(a1 & 0xffffu)); f[3] = bf2f((u16)(a1 >> 16));
    f[4] = bf2f((u16)(a2 & 0xffffu)); f[5] = bf2f((u16)(a2 >> 16));
    f[6] = bf2f((u16)(a3 & 0xffffu)); f[7] = bf2f((u16)(a3 >> 16));
}

// ---------------------------------------------------------------------------
// avgpool: xpT[b, c, m] = mean of x[b, c, 2gy:2gy+2, 2gx:2gx+2]; all f32.
// ---------------------------------------------------------------------------
__global__ __launch_bounds__(256) void avgpool_kernel(const float* __restrict__ x,
                                                      float* __restrict__ xpT) {
    int idx = blockIdx.x * 256 + threadIdx.x;  // over BATCH*CH*G
    if (idx >= BATCH * CH * G) return;
    int m = idx % G;
    int bc = idx / G;
    int gy = m / GW, gx = m % GW;
    const float* base = x + (size_t)bc * NTOK + (gy * 2) * WW + gx * 2;
    xpT[(size_t)bc * G + m] = 0.25f * (base[0] + base[1] + base[WW] + base[WW + 1]);
}

// ---------------------------------------------------------------------------
// gemm_kt: C[b, m, joff+j] = sum_k A[b, k, m] * Bw[k, j]
// A: [B, K, Mtot] f32 (K-major), Bw: [K, J] f32, C bf16 with row stride ldc.
// 64x64 tile, BK=16, 256 threads, 4x4 per thread.
// ---------------------------------------------------------------------------
__global__ __launch_bounds__(256) void gemm_kt(const float* __restrict__ A,
                                               const float* __restrict__ Bw,
                                               u16* __restrict__ C,
                                               int K, int Mtot, int J, int ldc, int joff) {
    __shared__ float As[16][64];
    __shared__ float Bs[16][64];
    int tid = threadIdx.x;
    int tx = tid & 15, ty = tid >> 4;  // tx -> j (lane-fastest for coalesced store), ty -> m
    int m0 = blockIdx.x * 64, j0 = blockIdx.y * 64, b = blockIdx.z;
    const float* Ab = A + (size_t)b * K * Mtot;
    float acc[4][4] = {};
    for (int k0 = 0; k0 < K; k0 += 16) {
        #pragma unroll
        for (int i = 0; i < 4; i++) {
            int e = tid + i * 256;
            int kk = e >> 6, mm = e & 63;
            As[kk][mm] = Ab[(size_t)(k0 + kk) * Mtot + m0 + mm];
            Bs[kk][mm] = Bw[(size_t)(k0 + kk) * J + j0 + mm];
        }
        __syncthreads();
        #pragma unroll
        for (int kk = 0; kk < 16; kk++) {
            float4 av = *(const float4*)&As[kk][ty * 4];
            float4 bv = *(const float4*)&Bs[kk][tx * 4];
            float am[4] = {av.x, av.y, av.z, av.w};
            float bj[4] = {bv.x, bv.y, bv.z, bv.w};
            #pragma unroll
            for (int mi = 0; mi < 4; mi++)
                #pragma unroll
                for (int ji = 0; ji < 4; ji++)
                    acc[mi][ji] += am[mi] * bj[ji];
        }
        __syncthreads();
    }
    #pragma unroll
    for (int mi = 0; mi < 4; mi++) {
        int m = m0 + ty * 4 + mi;
        uint2 pk;
        pk.x = (unsigned)f2bf(acc[mi][0]) | ((unsigned)f2bf(acc[mi][1]) << 16);
        pk.y = (unsigned)f2bf(acc[mi][2]) | ((unsigned)f2bf(acc[mi][3]) << 16);
        *(uint2*)&C[((size_t)b * Mtot + m) * ldc + joff + j0 + tx * 4] = pk;
    }
}

// ---------------------------------------------------------------------------
// gemm_proj: Out[b, cbase+j, m] = sum_k A[b, m, k]*Bw[k, j] + bias[j]
// A: [B, Mtot, K] bf16 row-major; Bw/bias f32; Out f32 [B, 384, NTOK].
// ---------------------------------------------------------------------------
__global__ __launch_bounds__(256) void gemm_proj(const u16* __restrict__ A,
                                                 const float* __restrict__ Bw,
                                                 const float* __restrict__ bias,
                                                 float* __restrict__ Out,
                                                 int Mtot, int K, int J, int cbase) {
    __shared__ float As[64][17];
    __shared__ float Bs[16][64];
    int tid = threadIdx.x;
    int tx = tid & 15, ty = tid >> 4;  // tx -> m (lane-fastest), ty -> j
    int m0 = blockIdx.x * 64, j0 = blockIdx.y * 64, b = blockIdx.z;
    const u16* Ab = A + (size_t)b * Mtot * K;
    float acc[4][4] = {};
    for (int k0 = 0; k0 < K; k0 += 16) {
        #pragma unroll
        for (int i = 0; i < 4; i++) {
            int e = tid + i * 256;
            int mm = e >> 4, kk = e & 15;
            As[mm][kk] = bf2f(Ab[(size_t)(m0 + mm) * K + k0 + kk]);
        }
        #pragma unroll
        for (int i = 0; i < 4; i++) {
            int e = tid + i * 256;
            int kk = e >> 6, jj = e & 63;
            Bs[kk][jj] = Bw[(size_t)(k0 + kk) * J + j0 + jj];
        }
        __syncthreads();
        #pragma unroll
        for (int kk = 0; kk < 16; kk++) {
            float am[4];
            #pragma unroll
            for (int mi = 0; mi < 4; mi++) am[mi] = As[tx * 4 + mi][kk];
            float4 bv = *(const float4*)&Bs[kk][ty * 4];
            float bj[4] = {bv.x, bv.y, bv.z, bv.w};
            #pragma unroll
            for (int mi = 0; mi < 4; mi++)
                #pragma unroll
                for (int ji = 0; ji < 4; ji++)
                    acc[mi][ji] += am[mi] * bj[ji];
        }
        __syncthreads();
    }
    #pragma unroll
    for (int ji = 0; ji < 4; ji++) {
        int j = j0 + ty * 4 + ji;
        float bb = bias[j];
        float4 o = make_float4(acc[0][ji] + bb, acc[1][ji] + bb,
                               acc[2][ji] + bb, acc[3][ji] + bb);
        *(float4*)&Out[((size_t)b * CH + cbase + j) * NTOK + m0 + tx * 4] = o;
    }
}

// ---------------------------------------------------------------------------
// hi_attn: one block (128 thr) per (b, window). tokf row layout [768]:
//   j = s*192 + h*32 + d for s in {q,k,v}; lo-q lives at 576+.
// ---------------------------------------------------------------------------
__global__ __launch_bounds__(128) void hi_attn(const u16* __restrict__ tokf,
                                               u16* __restrict__ hi_ao) {
    __shared__ float sq[4][576];
    __shared__ float satt[4][4];
    __shared__ float sp[4][4];
    int tid = threadIdx.x;
    int bg = blockIdx.x;
    int b = bg / G, g = bg % G;
    int gy = g / GW, gx = g % GW;

    for (int e = tid; e < 4 * 576; e += 128) {
        int t = e / 576, j = e % 576;
        int y = gy * 2 + (t >> 1), xx = gx * 2 + (t & 1);
        sq[t][j] = bf2f(tokf[((size_t)b * NTOK + y * WW + xx) * 768 + j]);
    }
    __syncthreads();

    for (int h = 0; h < HEADS; h++) {
        if (tid < 16) {
            int tq = tid >> 2, tm = tid & 3;
            const float* qp = &sq[tq][h * 32];
            const float* kp = &sq[tm][192 + h * 32];
            float s0 = 0, s1 = 0, s2 = 0, s3 = 0;
            #pragma unroll
            for (int d = 0; d < 32; d += 4) {
                s0 += qp[d] * kp[d];
                s1 += qp[d + 1] * kp[d + 1];
                s2 += qp[d + 2] * kp[d + 2];
                s3 += qp[d + 3] * kp[d + 3];
            }
            satt[tq][tm] = (s0 + s1 + s2 + s3) * SCALE;
        }
        __syncthreads();
        if (tid < 4) {
            float l0 = satt[tid][0], l1 = satt[tid][1], l2 = satt[tid][2], l3 = satt[tid][3];
            float mx = fmaxf(fmaxf(l0, l1), fmaxf(l2, l3));
            float e0 = __expf(l0 - mx), e1 = __expf(l1 - mx);
            float e2 = __expf(l2 - mx), e3 = __expf(l3 - mx);
            float inv = 1.0f / (e0 + e1 + e2 + e3);
            sp[tid][0] = e0 * inv; sp[tid][1] = e1 * inv;
            sp[tid][2] = e2 * inv; sp[tid][3] = e3 * inv;
        }
        __syncthreads();
        {
            int t = tid >> 5, d = tid & 31;
            float o = 0;
            #pragma unroll
            for (int mt = 0; mt < 4; mt++) o += sp[t][mt] * sq[mt][384 + h * 32 + d];
            int y = gy * 2 + (t >> 1), xx = gx * 2 + (t & 1);
            hi_ao[((size_t)b * NTOK + y * WW + xx) * 192 + h * 32 + d] = f2bf(o);
        }
        __syncthreads();
    }
}

// ---------------------------------------------------------------------------
// lo_attn: grid (NTOK/64, HEADS, BATCH), 256 thr = 4 waves.
// Lane owns one query; each wave handles 16 keys of each staged 64-key tile
// with its own online-softmax state; LDS merge at the end.
// ---------------------------------------------------------------------------
__global__ __launch_bounds__(256) void lo_attn(const u16* __restrict__ tokf,
                                               const u16* __restrict__ lkv,
                                               u16* __restrict__ lo_ao) {
    __shared__ float smem[8960];  // stage: 64*33*2=4224 | merge: 256+256+256*33=8960
    float* sk = smem;
    float* sv = smem + 64 * 33;
    int tid = threadIdx.x;
    int wave = tid >> 6, lane = tid & 63;
    int qt = blockIdx.x, h = blockIdx.y, b = blockIdx.z;
    int n = qt * 64 + lane;

    float q[32];
    {
        const u16* qp = tokf + ((size_t)b * NTOK + n) * 768 + 576 + h * 32;
        #pragma unroll
        for (int i = 0; i < 4; i++) {
            uint4 u = *(const uint4*)(qp + i * 8);
            unpack8(u, &q[i * 8]);
        }
    }

    float mrun = -1e30f, lrun = 0.f, acc[32];
    #pragma unroll
    for (int d = 0; d < 32; d++) acc[d] = 0.f;

    const u16* kvb = lkv + (size_t)b * G * 384;
    for (int m0 = 0; m0 < G; m0 += 64) {
        {   // stage 64 k rows + 64 v rows
            int r = tid >> 2, qq = tid & 3;
            const u16* kp = kvb + (size_t)(m0 + r) * 384 + h * 32 + qq * 8;
            uint4 ku = *(const uint4*)kp;
            uint4 vu = *(const uint4*)(kp + 192);
            unpack8(ku, &sk[r * 33 + qq * 8]);
            unpack8(vu, &sv[r * 33 + qq * 8]);
        }
        __syncthreads();
        for (int mm = wave * 16; mm < wave * 16 + 16; mm++) {
            const float* kr = &sk[mm * 33];
            float s0 = 0, s1 = 0, s2 = 0, s3 = 0;
            #pragma unroll
            for (int d = 0; d < 32; d += 4) {
                s0 += q[d] * kr[d];
                s1 += q[d + 1] * kr[d + 1];
                s2 += q[d + 2] * kr[d + 2];
                s3 += q[d + 3] * kr[d + 3];
            }
            float s = (s0 + s1 + s2 + s3) * SCALE;
            if (s > mrun) {
                float corr = __expf(mrun - s);
                lrun *= corr;
                #pragma unroll
                for (int d = 0; d < 32; d++) acc[d] *= corr;
                mrun = s;
            }
            float p = __expf(s - mrun);
            lrun += p;
            const float* vr = &sv[mm * 33];
            #pragma unroll
            for (int d = 0; d < 32; d++) acc[d] += p * vr[d];
        }
        __syncthreads();
    }

    // merge 4 per-wave partials
    float* rm = smem;            // [4][64]
    float* rl = smem + 256;      // [4][64]
    float* racc = smem + 512;    // [4][64][33]
    rm[wave * 64 + lane] = mrun;
    rl[wave * 64 + lane] = lrun;
    #pragma unroll
    for (int d = 0; d < 32; d++) racc[(wave * 64 + lane) * 33 + d] = acc[d];
    __syncthreads();
    if (tid < 64) {
        float M = rm[tid];
        M = fmaxf(M, rm[64 + tid]);
        M = fmaxf(M, rm[128 + tid]);
        M = fmaxf(M, rm[192 + tid]);
        float f[4], L = 0.f;
        #pragma unroll
        for (int w = 0; w < 4; w++) {
            f[w] = __expf(rm[w * 64 + tid] - M);
            L += rl[w * 64 + tid] * f[w];
        }
        float invL = 1.0f / L;
        int n2 = qt * 64 + tid;
        #pragma unroll
        for (int g2 = 0; g2 < 4; g2++) {
            unsigned pw[4];
            #pragma unroll
            for (int p2 = 0; p2 < 4; p2++) {
                int d = g2 * 8 + p2 * 2;
                float o0 = 0, o1 = 0;
                #pragma unroll
                for (int w = 0; w < 4; w++) {
                    const float* rr = &racc[(w * 64 + tid) * 33];
                    o0 += rr[d] * f[w];
                    o1 += rr[d + 1] * f[w];
                }
                pw[p2] = (unsigned)f2bf(o0 * invL) | ((unsigned)f2bf(o1 * invL) << 16);
            }
            uint4 uo = make_uint4(pw[0], pw[1], pw[2], pw[3]);
            *(uint4*)&lo_ao[((size_t)b * NTOK + n2) * 192 + h * 32 + g2 * 8] = uo;
        }
    }
}

// ---------------------------------------------------------------------------
extern "C" void kernel_launch(void* const* d_in, const int* in_sizes, int n_in,
                              void* d_out, int out_size, void* d_ws, size_t ws_size,
                              hipStream_t stream) {
    const float* x       = (const float*)d_in[0];
    const float* Wh_qkv  = (const float*)d_in[1];
    const float* Wh_proj = (const float*)d_in[2];
    const float* bh_proj = (const float*)d_in[3];
    const float* Wl_q    = (const float*)d_in[4];
    const float* Wl_kv   = (const float*)d_in[5];
    const float* Wl_proj = (const float*)d_in[6];
    const float* bl_proj = (const float*)d_in[7];
    float* out = (float*)d_out;

    // ws layout
    u16*   tokf  = (u16*)d_ws;                         // [B, NTOK, 768] bf16 (hi qkv | lo q)
    float* xpT   = (float*)(tokf + (size_t)BATCH * NTOK * 768);  // [B, 384, G] f32
    u16*   lkvb  = (u16*)(xpT + (size_t)BATCH * CH * G);         // [B, G, 384] bf16 (lo k|v)
    u16*   hi_ao = lkvb + (size_t)BATCH * G * 384;     // [B, NTOK, 192] bf16
    u16*   lo_ao = hi_ao + (size_t)BATCH * NTOK * 192; // [B, NTOK, 192] bf16

    avgpool_kernel<<<dim3((BATCH * CH * G + 255) / 256), dim3(256), 0, stream>>>(x, xpT);
    // token features: hi qkv (j 0..575), lo q (j 576..767)
    gemm_kt<<<dim3(NTOK / 64, 576 / 64, BATCH), dim3(256), 0, stream>>>(
        x, Wh_qkv, tokf, CH, NTOK, 576, 768, 0);
    gemm_kt<<<dim3(NTOK / 64, 192 / 64, BATCH), dim3(256), 0, stream>>>(
        x, Wl_q, tokf, CH, NTOK, 192, 768, 576);
    // lo k/v from pooled tokens
    gemm_kt<<<dim3(G / 64, 384 / 64, BATCH), dim3(256), 0, stream>>>(
        xpT, Wl_kv, lkvb, CH, G, 384, 384, 0);

    hi_attn<<<dim3(BATCH * G), dim3(128), 0, stream>>>(tokf, hi_ao);
    lo_attn<<<dim3(NTOK / 64, HEADS, BATCH), dim3(256), 0, stream>>>(tokf, lkvb, lo_ao);

    gemm_proj<<<dim3(NTOK / 64, 192 / 64, BATCH), dim3(256), 0, stream>>>(
        hi_ao, Wh_proj, bh_proj, out, NTOK, 192, 192, 0);
    gemm_proj<<<dim3(NTOK / 64, 192 / 64, BATCH), dim3(256), 0, stream>>>(
        lo_ao, Wl_proj, bl_proj, out, NTOK, 192, 192, 192);
}

// Round 4
// 492.544 us; speedup vs baseline: 2.5035x; 2.5035x over previous
//
#include <hip/hip_runtime.h>

typedef unsigned short u16;

#define DEV static __device__ __forceinline__

DEV float bf2f(u16 v) { unsigned x = ((unsigned)v) << 16; return __uint_as_float(x); }
DEV u16 f2bf(float f) {
    unsigned x = __float_as_uint(f);
    unsigned r = (x + 0x7fffu + ((x >> 16) & 1u)) >> 16;
    return (u16)r;
}

constexpr int BATCH = 2;
constexpr int CH    = 384;
constexpr int HH    = 96;
constexpr int WW    = 96;
constexpr int NTOK  = HH * WW;      // 9216
constexpr int GW    = 48;
constexpr int G     = GW * GW;      // 2304 pooled tokens (= M for lo-fi)
constexpr int HEADS = 6;
constexpr float SCALE = 0.17677669529663687f;  // 32^-0.5

typedef __attribute__((ext_vector_type(8))) short short8v;   // 8 bf16
typedef __attribute__((ext_vector_type(4))) float f32x4;

DEV f32x4 mfma16(short8v a, short8v b, f32x4 c) {
    return __builtin_amdgcn_mfma_f32_16x16x32_bf16(a, b, c, 0, 0, 0);
}

DEV void unpack8(uint4 u, float* f) {
    unsigned a0 = u.x, a1 = u.y, a2 = u.z, a3 = u.w;
    f[0] = bf2f((u16)(a0 & 0xffffu)); f[1] = bf2f((u16)(a0 >> 16));
    f[2] = bf2f((u16)(a1 & 0xffffu)); f[3] = bf2f((u16)(a1 >> 16));
    f[4] = bf2f((u16)(a2 & 0xffffu)); f[5] = bf2f((u16)(a2 >> 16));
    f[6] = bf2f((u16)(a3 & 0xffffu)); f[7] = bf2f((u16)(a3 >> 16));
}

// ---------------------------------------------------------------------------
// avgpool: xpT[b, c, m] = mean of x[b, c, 2gy:2gy+2, 2gx:2gx+2]; all f32.
// ---------------------------------------------------------------------------
__global__ __launch_bounds__(256) void avgpool_kernel(const float* __restrict__ x,
                                                      float* __restrict__ xpT) {
    int idx = blockIdx.x * 256 + threadIdx.x;  // over BATCH*CH*G
    if (idx >= BATCH * CH * G) return;
    int m = idx % G;
    int bc = idx / G;
    int gy = m / GW, gx = m % GW;
    const float* base = x + (size_t)bc * NTOK + (gy * 2) * WW + gx * 2;
    xpT[(size_t)bc * G + m] = 0.25f * (base[0] + base[1] + base[WW] + base[WW + 1]);
}

// ---------------------------------------------------------------------------
// gemm_kt: C[b, m, joff+j] = sum_k A[b, k, m] * Bw[k, j]
// A: [B, K, Mtot] f32 (K-major), Bw: [K, J] f32, C bf16 with row stride ldc.
// ---------------------------------------------------------------------------
__global__ __launch_bounds__(256) void gemm_kt(const float* __restrict__ A,
                                               const float* __restrict__ Bw,
                                               u16* __restrict__ C,
                                               int K, int Mtot, int J, int ldc, int joff) {
    __shared__ float As[16][64];
    __shared__ float Bs[16][64];
    int tid = threadIdx.x;
    int tx = tid & 15, ty = tid >> 4;
    int m0 = blockIdx.x * 64, j0 = blockIdx.y * 64, b = blockIdx.z;
    const float* Ab = A + (size_t)b * K * Mtot;
    float acc[4][4] = {};
    for (int k0 = 0; k0 < K; k0 += 16) {
        #pragma unroll
        for (int i = 0; i < 4; i++) {
            int e = tid + i * 256;
            int kk = e >> 6, mm = e & 63;
            As[kk][mm] = Ab[(size_t)(k0 + kk) * Mtot + m0 + mm];
            Bs[kk][mm] = Bw[(size_t)(k0 + kk) * J + j0 + mm];
        }
        __syncthreads();
        #pragma unroll
        for (int kk = 0; kk < 16; kk++) {
            float4 av = *(const float4*)&As[kk][ty * 4];
            float4 bv = *(const float4*)&Bs[kk][tx * 4];
            float am[4] = {av.x, av.y, av.z, av.w};
            float bj[4] = {bv.x, bv.y, bv.z, bv.w};
            #pragma unroll
            for (int mi = 0; mi < 4; mi++)
                #pragma unroll
                for (int ji = 0; ji < 4; ji++)
                    acc[mi][ji] += am[mi] * bj[ji];
        }
        __syncthreads();
    }
    #pragma unroll
    for (int mi = 0; mi < 4; mi++) {
        int m = m0 + ty * 4 + mi;
        uint2 pk;
        pk.x = (unsigned)f2bf(acc[mi][0]) | ((unsigned)f2bf(acc[mi][1]) << 16);
        pk.y = (unsigned)f2bf(acc[mi][2]) | ((unsigned)f2bf(acc[mi][3]) << 16);
        *(uint2*)&C[((size_t)b * Mtot + m) * ldc + joff + j0 + tx * 4] = pk;
    }
}

// ---------------------------------------------------------------------------
// gemm_proj: Out[b, cbase+j, m] = sum_k A[b, m, k]*Bw[k, j] + bias[j]
// A: [B, Mtot, K] bf16 row-major; Bw/bias f32; Out f32 [B, 384, NTOK].
// ---------------------------------------------------------------------------
__global__ __launch_bounds__(256) void gemm_proj(const u16* __restrict__ A,
                                                 const float* __restrict__ Bw,
                                                 const float* __restrict__ bias,
                                                 float* __restrict__ Out,
                                                 int Mtot, int K, int J, int cbase) {
    __shared__ float As[64][17];
    __shared__ float Bs[16][64];
    int tid = threadIdx.x;
    int tx = tid & 15, ty = tid >> 4;
    int m0 = blockIdx.x * 64, j0 = blockIdx.y * 64, b = blockIdx.z;
    const u16* Ab = A + (size_t)b * Mtot * K;
    float acc[4][4] = {};
    for (int k0 = 0; k0 < K; k0 += 16) {
        #pragma unroll
        for (int i = 0; i < 4; i++) {
            int e = tid + i * 256;
            int mm = e >> 4, kk = e & 15;
            As[mm][kk] = bf2f(Ab[(size_t)(m0 + mm) * K + k0 + kk]);
        }
        #pragma unroll
        for (int i = 0; i < 4; i++) {
            int e = tid + i * 256;
            int kk = e >> 6, jj = e & 63;
            Bs[kk][jj] = Bw[(size_t)(k0 + kk) * J + j0 + jj];
        }
        __syncthreads();
        #pragma unroll
        for (int kk = 0; kk < 16; kk++) {
            float am[4];
            #pragma unroll
            for (int mi = 0; mi < 4; mi++) am[mi] = As[tx * 4 + mi][kk];
            float4 bv = *(const float4*)&Bs[kk][ty * 4];
            float bj[4] = {bv.x, bv.y, bv.z, bv.w};
            #pragma unroll
            for (int mi = 0; mi < 4; mi++)
                #pragma unroll
                for (int ji = 0; ji < 4; ji++)
                    acc[mi][ji] += am[mi] * bj[ji];
        }
        __syncthreads();
    }
    #pragma unroll
    for (int ji = 0; ji < 4; ji++) {
        int j = j0 + ty * 4 + ji;
        float bb = bias[j];
        float4 o = make_float4(acc[0][ji] + bb, acc[1][ji] + bb,
                               acc[2][ji] + bb, acc[3][ji] + bb);
        *(float4*)&Out[((size_t)b * CH + cbase + j) * NTOK + m0 + tx * 4] = o;
    }
}

// ---------------------------------------------------------------------------
// hi_attn: one block (128 thr) per (b, window).
// ---------------------------------------------------------------------------
__global__ __launch_bounds__(128) void hi_attn(const u16* __restrict__ tokf,
                                               u16* __restrict__ hi_ao) {
    __shared__ float sq[4][576];
    __shared__ float satt[4][4];
    __shared__ float sp[4][4];
    int tid = threadIdx.x;
    int bg = blockIdx.x;
    int b = bg / G, g = bg % G;
    int gy = g / GW, gx = g % GW;

    for (int e = tid; e < 4 * 576; e += 128) {
        int t = e / 576, j = e % 576;
        int y = gy * 2 + (t >> 1), xx = gx * 2 + (t & 1);
        sq[t][j] = bf2f(tokf[((size_t)b * NTOK + y * WW + xx) * 768 + j]);
    }
    __syncthreads();

    for (int h = 0; h < HEADS; h++) {
        if (tid < 16) {
            int tq = tid >> 2, tm = tid & 3;
            const float* qp = &sq[tq][h * 32];
            const float* kp = &sq[tm][192 + h * 32];
            float s0 = 0, s1 = 0, s2 = 0, s3 = 0;
            #pragma unroll
            for (int d = 0; d < 32; d += 4) {
                s0 += qp[d] * kp[d];
                s1 += qp[d + 1] * kp[d + 1];
                s2 += qp[d + 2] * kp[d + 2];
                s3 += qp[d + 3] * kp[d + 3];
            }
            satt[tq][tm] = (s0 + s1 + s2 + s3) * SCALE;
        }
        __syncthreads();
        if (tid < 4) {
            float l0 = satt[tid][0], l1 = satt[tid][1], l2 = satt[tid][2], l3 = satt[tid][3];
            float mx = fmaxf(fmaxf(l0, l1), fmaxf(l2, l3));
            float e0 = __expf(l0 - mx), e1 = __expf(l1 - mx);
            float e2 = __expf(l2 - mx), e3 = __expf(l3 - mx);
            float inv = 1.0f / (e0 + e1 + e2 + e3);
            sp[tid][0] = e0 * inv; sp[tid][1] = e1 * inv;
            sp[tid][2] = e2 * inv; sp[tid][3] = e3 * inv;
        }
        __syncthreads();
        {
            int t = tid >> 5, d = tid & 31;
            float o = 0;
            #pragma unroll
            for (int mt = 0; mt < 4; mt++) o += sp[t][mt] * sq[mt][384 + h * 32 + d];
            int y = gy * 2 + (t >> 1), xx = gx * 2 + (t & 1);
            hi_ao[((size_t)b * NTOK + y * WW + xx) * 192 + h * 32 + d] = f2bf(o);
        }
        __syncthreads();
    }
}

// ---------------------------------------------------------------------------
// lo_attn (MFMA flash): grid (NTOK/64, HEADS, BATCH), 256 thr = 4 waves.
// Each wave owns 16 queries (A-frag), iterates all 2304 keys in 64-key tiles.
// K staged [64][40] bf16, V^T staged [32][72] bf16, P staged per-wave [16][72].
// mfma_f32_16x16x32_bf16 frag maps: A[row=l&15][k=(l>>4)*8+j],
// B[k=(l>>4)*8+j][col=l&15], C/D[row=(l>>4)*4+r][col=l&15].
// ---------------------------------------------------------------------------
constexpr int KLD = 40;   // K-tile leading dim (bf16 elems): 80B rows, 16B-aligned
constexpr int VLD = 72;   // V^T / P leading dim: 144B rows, 16B-aligned

__global__ __launch_bounds__(256) void lo_attn(const u16* __restrict__ tokf,
                                               const u16* __restrict__ lkv,
                                               u16* __restrict__ lo_ao) {
    __shared__ u16 skl[64 * KLD];        // K tile  [key][d]
    __shared__ u16 svt[32 * VLD];        // V^T tile [d][key]
    __shared__ u16 spl[4][16 * VLD];     // per-wave P [q][key]
    int tid = threadIdx.x, wave = tid >> 6, lane = tid & 63;
    int l15 = lane & 15, q4 = lane >> 4;
    int qt = blockIdx.x, h = blockIdx.y, b = blockIdx.z;

    const f32x4 zero4 = {0.f, 0.f, 0.f, 0.f};

    // Q A-frag: row = l15 (query), k = q4*8 + j
    int nq_load = qt * 64 + wave * 16 + l15;
    short8v qa = *(const short8v*)&tokf[((size_t)b * NTOK + nq_load) * 768 + 576 + h * 32 + q4 * 8];

    f32x4 accO[2];
    accO[0] = zero4;
    accO[1] = zero4;
    float mrow[4] = {-1e30f, -1e30f, -1e30f, -1e30f};
    float lrow[4] = {0.f, 0.f, 0.f, 0.f};

    const u16* kvb = lkv + (size_t)b * G * 384;
    int srow = tid >> 2, spart = tid & 3;
    u16* pl = &spl[wave][0];

    for (int m0 = 0; m0 < G; m0 += 64) {
        // ---- stage K + V^T (all 256 threads) ----
        {
            const u16* gp = kvb + (size_t)(m0 + srow) * 384 + h * 32 + spart * 8;
            uint4 kq = *(const uint4*)gp;
            uint4 vq = *(const uint4*)(gp + 192);
            *(uint4*)&skl[srow * KLD + spart * 8] = kq;
            u16 vt[8];
            *(uint4*)vt = vq;
            #pragma unroll
            for (int j = 0; j < 8; j++) svt[(spart * 8 + j) * VLD + srow] = vt[j];
        }
        __syncthreads();

        // ---- QK^T: 4 MFMAs ----
        f32x4 s[4];
        #pragma unroll
        for (int g = 0; g < 4; g++) {
            short8v kb = *(const short8v*)&skl[(g * 16 + l15) * KLD + q4 * 8];
            s[g] = mfma16(qa, kb, zero4);
        }

        // ---- online softmax ----
        #pragma unroll
        for (int r = 0; r < 4; r++) {
            float pm = fmaxf(fmaxf(s[0][r], s[1][r]), fmaxf(s[2][r], s[3][r])) * SCALE;
            pm = fmaxf(pm, __shfl_xor(pm, 1));
            pm = fmaxf(pm, __shfl_xor(pm, 2));
            pm = fmaxf(pm, __shfl_xor(pm, 4));
            pm = fmaxf(pm, __shfl_xor(pm, 8));
            float mnew = fmaxf(mrow[r], pm);
            float corr = __expf(mrow[r] - mnew);
            mrow[r] = mnew;
            lrow[r] *= corr;
            accO[0][r] *= corr;
            accO[1][r] *= corr;
            float ps = 0.f;
            #pragma unroll
            for (int g = 0; g < 4; g++) {
                float p = __expf(s[g][r] * SCALE - mnew);
                ps += p;
                pl[(q4 * 4 + r) * VLD + g * 16 + l15] = f2bf(p);
            }
            ps += __shfl_xor(ps, 1);
            ps += __shfl_xor(ps, 2);
            ps += __shfl_xor(ps, 4);
            ps += __shfl_xor(ps, 8);
            lrow[r] += ps;
        }

        // ---- PV: 4 MFMAs (same-wave LDS dependency, no barrier needed) ----
        #pragma unroll
        for (int ks = 0; ks < 2; ks++) {
            short8v pa = *(const short8v*)&pl[l15 * VLD + ks * 32 + q4 * 8];
            #pragma unroll
            for (int cg = 0; cg < 2; cg++) {
                short8v vb = *(const short8v*)&svt[(cg * 16 + l15) * VLD + ks * 32 + q4 * 8];
                accO[cg] = mfma16(pa, vb, accO[cg]);
            }
        }
        __syncthreads();
    }

    // ---- epilogue ----
    #pragma unroll
    for (int r = 0; r < 4; r++) {
        float inv = 1.0f / lrow[r];
        int nq = qt * 64 + wave * 16 + q4 * 4 + r;
        u16* op = &lo_ao[((size_t)b * NTOK + nq) * 192 + h * 32];
        op[l15] = f2bf(accO[0][r] * inv);
        op[16 + l15] = f2bf(accO[1][r] * inv);
    }
}

// ---------------------------------------------------------------------------
extern "C" void kernel_launch(void* const* d_in, const int* in_sizes, int n_in,
                              void* d_out, int out_size, void* d_ws, size_t ws_size,
                              hipStream_t stream) {
    const float* x       = (const float*)d_in[0];
    const float* Wh_qkv  = (const float*)d_in[1];
    const float* Wh_proj = (const float*)d_in[2];
    const float* bh_proj = (const float*)d_in[3];
    const float* Wl_q    = (const float*)d_in[4];
    const float* Wl_kv   = (const float*)d_in[5];
    const float* Wl_proj = (const float*)d_in[6];
    const float* bl_proj = (const float*)d_in[7];
    float* out = (float*)d_out;

    // ws layout
    u16*   tokf  = (u16*)d_ws;                         // [B, NTOK, 768] bf16 (hi qkv | lo q)
    float* xpT   = (float*)(tokf + (size_t)BATCH * NTOK * 768);  // [B, 384, G] f32
    u16*   lkvb  = (u16*)(xpT + (size_t)BATCH * CH * G);         // [B, G, 384] bf16 (lo k|v)
    u16*   hi_ao = lkvb + (size_t)BATCH * G * 384;     // [B, NTOK, 192] bf16
    u16*   lo_ao = hi_ao + (size_t)BATCH * NTOK * 192; // [B, NTOK, 192] bf16

    avgpool_kernel<<<dim3((BATCH * CH * G + 255) / 256), dim3(256), 0, stream>>>(x, xpT);
    gemm_kt<<<dim3(NTOK / 64, 576 / 64, BATCH), dim3(256), 0, stream>>>(
        x, Wh_qkv, tokf, CH, NTOK, 576, 768, 0);
    gemm_kt<<<dim3(NTOK / 64, 192 / 64, BATCH), dim3(256), 0, stream>>>(
        x, Wl_q, tokf, CH, NTOK, 192, 768, 576);
    gemm_kt<<<dim3(G / 64, 384 / 64, BATCH), dim3(256), 0, stream>>>(
        xpT, Wl_kv, lkvb, CH, G, 384, 384, 0);

    hi_attn<<<dim3(BATCH * G), dim3(128), 0, stream>>>(tokf, hi_ao);
    lo_attn<<<dim3(NTOK / 64, HEADS, BATCH), dim3(256), 0, stream>>>(tokf, lkvb, lo_ao);

    gemm_proj<<<dim3(NTOK / 64, 192 / 64, BATCH), dim3(256), 0, stream>>>(
        hi_ao, Wh_proj, bh_proj, out, NTOK, 192, 192, 0);
    gemm_proj<<<dim3(NTOK / 64, 192 / 64, BATCH), dim3(256), 0, stream>>>(
        lo_ao, Wl_proj, bl_proj, out, NTOK, 192, 192, 192);
}

// Round 5
// 201.315 us; speedup vs baseline: 6.1251x; 2.4466x over previous
//
#include <hip/hip_runtime.h>

typedef unsigned short u16;

#define DEV static __device__ __forceinline__

DEV float bf2f(u16 v) { unsigned x = ((unsigned)v) << 16; return __uint_as_float(x); }
DEV u16 f2bf(float f) {
    unsigned x = __float_as_uint(f);
    unsigned r = (x + 0x7fffu + ((x >> 16) & 1u)) >> 16;
    return (u16)r;
}

constexpr int BATCH = 2;
constexpr int CH    = 384;
constexpr int HH    = 96;
constexpr int WW    = 96;
constexpr int NTOK  = HH * WW;      // 9216
constexpr int GW    = 48;
constexpr int G     = GW * GW;      // 2304 pooled tokens
constexpr int HEADS = 6;
constexpr float SCALE = 0.17677669529663687f;  // 32^-0.5

typedef __attribute__((ext_vector_type(8))) short short8v;   // 8 bf16
typedef __attribute__((ext_vector_type(4))) float f32x4;

DEV f32x4 mfma16(short8v a, short8v b, f32x4 c) {
    return __builtin_amdgcn_mfma_f32_16x16x32_bf16(a, b, c, 0, 0, 0);
}

DEV unsigned cvtpk_bf16(float a, float b) {
    unsigned r;
    asm("v_cvt_pk_bf16_f32 %0, %1, %2" : "=v"(r) : "v"(a), "v"(b));
    return r;
}

DEV void unpack8(uint4 u, float* f) {
    unsigned a0 = u.x, a1 = u.y, a2 = u.z, a3 = u.w;
    f[0] = bf2f((u16)(a0 & 0xffffu)); f[1] = bf2f((u16)(a0 >> 16));
    f[2] = bf2f((u16)(a1 & 0xffffu)); f[3] = bf2f((u16)(a1 >> 16));
    f[4] = bf2f((u16)(a2 & 0xffffu)); f[5] = bf2f((u16)(a2 >> 16));
    f[6] = bf2f((u16)(a3 & 0xffffu)); f[7] = bf2f((u16)(a3 >> 16));
}

// ---------------------------------------------------------------------------
// avgpool: xpT[b, c, m] = mean over 2x2 window; f32 in/out (k-major).
// ---------------------------------------------------------------------------
__global__ __launch_bounds__(256) void avgpool_kernel(const float* __restrict__ x,
                                                      float* __restrict__ xpT) {
    int idx = blockIdx.x * 256 + threadIdx.x;
    if (idx >= BATCH * CH * G) return;
    int m = idx % G;
    int bc = idx / G;
    int gy = m / GW, gx = m % GW;
    const float* base = x + (size_t)bc * NTOK + (gy * 2) * WW + gx * 2;
    xpT[(size_t)bc * G + m] = 0.25f * (base[0] + base[1] + base[WW] + base[WW + 1]);
}

// ---------------------------------------------------------------------------
// transpose_f32_bf16: dst[c][r] = (bf16)src[r][c]. 32x32 tiles.
// grid (C/32, R/32, B). src stride sb (f32 elems), dst stride db (bf16 elems).
// ---------------------------------------------------------------------------
__global__ __launch_bounds__(256) void transpose_f32_bf16(const float* __restrict__ src,
        u16* __restrict__ dst, int R, int C, size_t sb, size_t db) {
    __shared__ float ts[32][33];
    int c0 = blockIdx.x * 32, r0 = blockIdx.y * 32, b = blockIdx.z;
    int tid = threadIdx.x;
    int row = tid >> 3, cg = tid & 7;
    float4 v = *(const float4*)&src[b * sb + (size_t)(r0 + row) * C + c0 + cg * 4];
    ts[row][cg * 4 + 0] = v.x; ts[row][cg * 4 + 1] = v.y;
    ts[row][cg * 4 + 2] = v.z; ts[row][cg * 4 + 3] = v.w;
    __syncthreads();
    int cc = tid >> 3, rg = tid & 7;
    uint2 u;
    u.x = (unsigned)f2bf(ts[rg * 4 + 0][cc]) | ((unsigned)f2bf(ts[rg * 4 + 1][cc]) << 16);
    u.y = (unsigned)f2bf(ts[rg * 4 + 2][cc]) | ((unsigned)f2bf(ts[rg * 4 + 3][cc]) << 16);
    *(uint2*)&dst[b * db + (size_t)(c0 + cc) * R + r0 + rg * 4] = u;
}

// ---------------------------------------------------------------------------
// gemm_rk: OUT[b][(cb + q0+q)*ldp + p0+p] = sum_k P[p][k] * Q[q][k] (+bias[q])
// P: bf16 [Ptot][K] rows (batch stride pbs), Q: bf16 [Qtot][K] (batch stride qbs).
// Both frags read k-contiguous. Output: lane holds 4 consecutive p per q.
// grid (Ptot/64, Qtot/64, B), 256 threads (4 waves; wave owns 16 p-rows).
// ---------------------------------------------------------------------------
template<bool F32OUT>
__global__ __launch_bounds__(256) void gemm_rk(const u16* __restrict__ P, size_t pbs,
        const u16* __restrict__ Q, size_t qbs, int K,
        void* __restrict__ O, size_t obs, int ldp, int cb,
        const float* __restrict__ bias) {
    __shared__ u16 pt[64 * 40];
    __shared__ u16 qt[64 * 40];
    int tid = threadIdx.x, w = tid >> 6, lane = tid & 63;
    int l15 = lane & 15, q4 = lane >> 4;
    int p0 = blockIdx.x * 64, q0 = blockIdx.y * 64, b = blockIdx.z;
    const u16* Pb = P + (size_t)b * pbs;
    const u16* Qb = Q + (size_t)b * qbs;
    int lr = tid >> 2, lc = tid & 3;

    const f32x4 zero4 = {0.f, 0.f, 0.f, 0.f};
    f32x4 acc[4];
    acc[0] = zero4; acc[1] = zero4; acc[2] = zero4; acc[3] = zero4;

    uint4 pv = *(const uint4*)&Pb[(size_t)(p0 + lr) * K + lc * 8];
    uint4 qv = *(const uint4*)&Qb[(size_t)(q0 + lr) * K + lc * 8];
    for (int k0 = 0; k0 < K; k0 += 32) {
        __syncthreads();
        *(uint4*)&pt[lr * 40 + lc * 8] = pv;
        *(uint4*)&qt[lr * 40 + lc * 8] = qv;
        if (k0 + 32 < K) {
            pv = *(const uint4*)&Pb[(size_t)(p0 + lr) * K + k0 + 32 + lc * 8];
            qv = *(const uint4*)&Qb[(size_t)(q0 + lr) * K + k0 + 32 + lc * 8];
        }
        __syncthreads();
        short8v pa = *(const short8v*)&pt[(w * 16 + l15) * 40 + q4 * 8];
        #pragma unroll
        for (int qg = 0; qg < 4; qg++) {
            short8v qb = *(const short8v*)&qt[(qg * 16 + l15) * 40 + q4 * 8];
            acc[qg] = mfma16(pa, qb, acc[qg]);
        }
    }
    #pragma unroll
    for (int qg = 0; qg < 4; qg++) {
        int q = q0 + qg * 16 + l15;
        int p = p0 + w * 16 + q4 * 4;
        if (F32OUT) {
            float bb = bias[q];
            float* Ob = (float*)O + (size_t)b * obs;
            float4 o = make_float4(acc[qg][0] + bb, acc[qg][1] + bb,
                                   acc[qg][2] + bb, acc[qg][3] + bb);
            *(float4*)&Ob[(size_t)(cb + q) * ldp + p] = o;
        } else {
            u16* Ob = (u16*)O + (size_t)b * obs;
            uint2 pk;
            pk.x = (unsigned)f2bf(acc[qg][0]) | ((unsigned)f2bf(acc[qg][1]) << 16);
            pk.y = (unsigned)f2bf(acc[qg][2]) | ((unsigned)f2bf(acc[qg][3]) << 16);
            *(uint2*)&Ob[(size_t)(cb + q) * ldp + p] = pk;
        }
    }
}

// ---------------------------------------------------------------------------
// hi_attn: one block (128 thr) per (b, window); all 6 heads concurrent, 3 barriers.
// ---------------------------------------------------------------------------
__global__ __launch_bounds__(128) void hi_attn(const u16* __restrict__ tokf,
                                               u16* __restrict__ hi_ao) {
    __shared__ float sq[4][576];
    __shared__ float satt[HEADS][4][4];
    __shared__ float sp[HEADS][4][4];
    int tid = threadIdx.x;
    int bg = blockIdx.x;
    int b = bg / G, g = bg % G;
    int gy = g / GW, gx = g % GW;

    for (int c = tid; c < 288; c += 128) {
        int t = c / 72, j8 = c - t * 72;
        int n = (gy * 2 + (t >> 1)) * WW + gx * 2 + (t & 1);
        uint4 u = *(const uint4*)&tokf[((size_t)b * NTOK + n) * 768 + j8 * 8];
        unpack8(u, &sq[t][j8 * 8]);
    }
    __syncthreads();

    if (tid < 96) {
        int h = tid >> 4, tq = (tid >> 2) & 3, tm = tid & 3;
        const float* qp = &sq[tq][h * 32];
        const float* kp = &sq[tm][192 + h * 32];
        float s0 = 0, s1 = 0, s2 = 0, s3 = 0;
        #pragma unroll
        for (int d = 0; d < 32; d += 4) {
            s0 += qp[d] * kp[d];
            s1 += qp[d + 1] * kp[d + 1];
            s2 += qp[d + 2] * kp[d + 2];
            s3 += qp[d + 3] * kp[d + 3];
        }
        satt[h][tq][tm] = (s0 + s1 + s2 + s3) * SCALE;
    }
    __syncthreads();
    if (tid < 24) {
        int h = tid >> 2, t = tid & 3;
        float l0 = satt[h][t][0], l1 = satt[h][t][1], l2 = satt[h][t][2], l3 = satt[h][t][3];
        float mx = fmaxf(fmaxf(l0, l1), fmaxf(l2, l3));
        float e0 = __expf(l0 - mx), e1 = __expf(l1 - mx);
        float e2 = __expf(l2 - mx), e3 = __expf(l3 - mx);
        float inv = 1.0f / (e0 + e1 + e2 + e3);
        sp[h][t][0] = e0 * inv; sp[h][t][1] = e1 * inv;
        sp[h][t][2] = e2 * inv; sp[h][t][3] = e3 * inv;
    }
    __syncthreads();
    {
        int t = tid >> 5, d = tid & 31;
        int n = (gy * 2 + (t >> 1)) * WW + gx * 2 + (t & 1);
        u16* op = &hi_ao[((size_t)b * NTOK + n) * 192];
        #pragma unroll
        for (int h = 0; h < HEADS; h++) {
            float o = sp[h][t][0] * sq[0][384 + h * 32 + d]
                    + sp[h][t][1] * sq[1][384 + h * 32 + d]
                    + sp[h][t][2] * sq[2][384 + h * 32 + d]
                    + sp[h][t][3] * sq[3][384 + h * 32 + d];
            op[h * 32 + d] = f2bf(o);
        }
    }
}

// ---------------------------------------------------------------------------
// lo_attn (MFMA flash, swapped QK^T): grid (NTOK/64, HEADS, BATCH), 256 thr.
// K: lkK[b][m][192] rows; V: lvT[b][192 rows=h*32+d][2304].
// LDS: skl [64][32] linear; svt XOR-swizzled phys(d,key)=d*64+(key^((d&7)*8));
// spl per-wave [16 q][72] for P round-trip.
// Swapped QK: s = mfma(K, Q) -> D[key][q]: lane(q4,l15) holds
//   s[g][r] = S[key=g*16+q4*4+r][q=l15]  => softmax per-query is lane-local.
// PV: unswapped (r4-verified): D[q][d], rows q=q4*4+r, col d=cg*16+l15.
// ---------------------------------------------------------------------------
__global__ __launch_bounds__(256) void lo_attn(const u16* __restrict__ tokf,
                                               const u16* __restrict__ lkK,
                                               const u16* __restrict__ lvT,
                                               u16* __restrict__ lo_ao) {
    __shared__ u16 skl[64 * 32];
    __shared__ u16 svt[32 * 64];
    __shared__ u16 spl[4][16 * 72];
    int tid = threadIdx.x, w = tid >> 6, lane = tid & 63;
    int l15 = lane & 15, q4 = lane >> 4;
    int qt = blockIdx.x, h = blockIdx.y, b = blockIdx.z;

    const f32x4 zero4 = {0.f, 0.f, 0.f, 0.f};

    int nq = qt * 64 + w * 16 + l15;
    short8v qa = *(const short8v*)&tokf[((size_t)b * NTOK + nq) * 768 + 576 + h * 32 + q4 * 8];

    f32x4 accO[2];
    accO[0] = zero4; accO[1] = zero4;
    float mrow = -1e30f, lrow = 0.f;

    // staging addresses
    int kkey = tid >> 2, kpart = tid & 3;
    const u16* ksrc = lkK + ((size_t)b * G + kkey) * 192 + h * 32 + kpart * 8;
    int vd = tid >> 3, vc = tid & 7;
    const u16* vsrc = lvT + ((size_t)b * 192 + h * 32 + vd) * G + vc * 8;
    u16* kdst = &skl[tid * 8];
    u16* vdst = &svt[vd * 64 + ((vc ^ (vd & 7)) * 8)];
    u16* pl = &spl[w][0];

    uint4 kreg = *(const uint4*)ksrc;
    uint4 vreg = *(const uint4*)vsrc;

    for (int t = 0; t < G / 64; t++) {
        __syncthreads();
        *(uint4*)kdst = kreg;
        *(uint4*)vdst = vreg;
        if (t + 1 < G / 64) {
            kreg = *(const uint4*)(ksrc + (size_t)(t + 1) * 64 * 192);
            vreg = *(const uint4*)(vsrc + (t + 1) * 64);
        }
        __syncthreads();

        // ---- QK^T (swapped): s[g] = K_g * Q ----
        f32x4 s[4];
        #pragma unroll
        for (int g = 0; g < 4; g++) {
            short8v kb = *(const short8v*)&skl[(g * 16 + l15) * 32 + q4 * 8];
            s[g] = mfma16(kb, qa, zero4);
        }

        // ---- online softmax (per-query lane-local; reduce across q4 lanes) ----
        float pm = s[0][0];
        #pragma unroll
        for (int g = 0; g < 4; g++)
            #pragma unroll
            for (int r = 0; r < 4; r++) pm = fmaxf(pm, s[g][r]);
        pm *= SCALE;
        pm = fmaxf(pm, __shfl_xor(pm, 16));
        pm = fmaxf(pm, __shfl_xor(pm, 32));
        float mnew = fmaxf(mrow, pm);
        float corr = __expf(mrow - mnew);
        mrow = mnew;

        float p[4][4];
        float ps = 0.f;
        #pragma unroll
        for (int g = 0; g < 4; g++)
            #pragma unroll
            for (int r = 0; r < 4; r++) {
                float e = __expf(fmaf(s[g][r], SCALE, -mnew));
                p[g][r] = e;
                ps += e;
            }
        ps += __shfl_xor(ps, 16);
        ps += __shfl_xor(ps, 32);
        lrow = lrow * corr + ps;

        // rescale accO (rows are q=q4*4+r; corr lives at lane l15=q)
        #pragma unroll
        for (int r = 0; r < 4; r++) {
            float cr = __shfl(corr, q4 * 4 + r);
            accO[0][r] *= cr;
            accO[1][r] *= cr;
        }

        // pack P -> per-wave LDS [q][key]
        #pragma unroll
        for (int g = 0; g < 4; g++) {
            uint2 pk;
            pk.x = cvtpk_bf16(p[g][0], p[g][1]);
            pk.y = cvtpk_bf16(p[g][2], p[g][3]);
            *(uint2*)&pl[l15 * 72 + g * 16 + q4 * 4] = pk;
        }

        // ---- PV ----
        #pragma unroll
        for (int ks = 0; ks < 2; ks++) {
            short8v pa = *(const short8v*)&pl[l15 * 72 + ks * 32 + q4 * 8];
            #pragma unroll
            for (int cg = 0; cg < 2; cg++) {
                int d = cg * 16 + l15;
                short8v vb = *(const short8v*)&svt[d * 64 + (((ks * 32 + q4 * 8)) ^ ((l15 & 7) * 8))];
                accO[cg] = mfma16(pa, vb, accO[cg]);
            }
        }
    }

    // ---- epilogue ----
    float inv = 1.0f / lrow;
    #pragma unroll
    for (int r = 0; r < 4; r++) {
        float ir = __shfl(inv, q4 * 4 + r);
        int n = qt * 64 + w * 16 + q4 * 4 + r;
        u16* op = &lo_ao[((size_t)b * NTOK + n) * 192 + h * 32];
        op[l15] = f2bf(accO[0][r] * ir);
        op[16 + l15] = f2bf(accO[1][r] * ir);
    }
}

// ---------------------------------------------------------------------------
extern "C" void kernel_launch(void* const* d_in, const int* in_sizes, int n_in,
                              void* d_out, int out_size, void* d_ws, size_t ws_size,
                              hipStream_t stream) {
    const float* x       = (const float*)d_in[0];
    const float* Wh_qkv  = (const float*)d_in[1];
    const float* Wh_proj = (const float*)d_in[2];
    const float* bh_proj = (const float*)d_in[3];
    const float* Wl_q    = (const float*)d_in[4];
    const float* Wl_kv   = (const float*)d_in[5];
    const float* Wl_proj = (const float*)d_in[6];
    const float* bl_proj = (const float*)d_in[7];
    float* out = (float*)d_out;

    // ---- workspace layout (bytes) ----
    char* ws = (char*)d_ws;
    u16*   tokf  = (u16*)ws;                               // [2][9216][768] bf16  28,311,552
    char*  ws1   = ws + (size_t)28311552;
    u16*   xT    = (u16*)ws1;                              // [2][9216][384] bf16  14,155,776
    u16*   hi_ao = (u16*)ws1;                              // overlay after tokf GEMM
    u16*   lo_ao = (u16*)(ws1 + 7077888);
    char*  ws2   = ws1 + (size_t)14155776;
    float* xpT   = (float*)ws2;                            // [2][384][2304] f32   7,077,888
    u16*   lkK   = (u16*)ws2;                              // overlay after xpool transpose
    u16*   lvT   = (u16*)(ws2 + 1769472);
    char*  ws3   = ws2 + (size_t)7077888;
    u16*   xpool = (u16*)ws3;                              // [2][2304][384] bf16  3,538,944
    char*  ws4   = ws3 + (size_t)3538944;
    u16*   WT768 = (u16*)ws4;                              // [768][384]           589,824
    u16*   WlkvT = WT768 + 768 * 384;                      // [384][384]           294,912
    u16*   WhpT  = WlkvT + 384 * 384;                      // [192][192]
    u16*   WlpT  = WhpT + 192 * 192;                       // [192][192]
    u16*   WlkT  = WlkvT;                                  // rows 0..191
    u16*   WvT   = WlkvT + 192 * 384;                      // rows 192..383

    // ---- weight transposes ----
    transpose_f32_bf16<<<dim3(576 / 32, 384 / 32, 1), 256, 0, stream>>>(
        Wh_qkv, WT768, 384, 576, 0, 0);
    transpose_f32_bf16<<<dim3(192 / 32, 384 / 32, 1), 256, 0, stream>>>(
        Wl_q, WT768 + 576 * 384, 384, 192, 0, 0);
    transpose_f32_bf16<<<dim3(384 / 32, 384 / 32, 1), 256, 0, stream>>>(
        Wl_kv, WlkvT, 384, 384, 0, 0);
    transpose_f32_bf16<<<dim3(192 / 32, 192 / 32, 1), 256, 0, stream>>>(
        Wh_proj, WhpT, 192, 192, 0, 0);
    transpose_f32_bf16<<<dim3(192 / 32, 192 / 32, 1), 256, 0, stream>>>(
        Wl_proj, WlpT, 192, 192, 0, 0);

    // ---- activations: pool + transposes ----
    avgpool_kernel<<<dim3((BATCH * CH * G + 255) / 256), 256, 0, stream>>>(x, xpT);
    transpose_f32_bf16<<<dim3(NTOK / 32, CH / 32, BATCH), 256, 0, stream>>>(
        x, xT, CH, NTOK, (size_t)CH * NTOK, (size_t)NTOK * CH);
    transpose_f32_bf16<<<dim3(G / 32, CH / 32, BATCH), 256, 0, stream>>>(
        xpT, xpool, CH, G, (size_t)CH * G, (size_t)G * CH);

    // ---- GEMMs (MFMA) ----
    // tokf[n][j] = xT[n][k] . WT768[j][k]   (p=j from WT768, q=n from xT)
    gemm_rk<false><<<dim3(768 / 64, NTOK / 64, BATCH), 256, 0, stream>>>(
        WT768, 0, xT, (size_t)NTOK * CH, CH, tokf, (size_t)NTOK * 768, 768, 0, nullptr);
    // lkK[m][d] = xpool[m][k] . WlkT[d][k]  (p=d, q=m)
    gemm_rk<false><<<dim3(192 / 64, G / 64, BATCH), 256, 0, stream>>>(
        WlkT, 0, xpool, (size_t)G * CH, CH, lkK, (size_t)G * 192, 192, 0, nullptr);
    // lvT[jj][m] = xpool[m][k] . WvT[jj][k] (p=m, q=jj)
    gemm_rk<false><<<dim3(G / 64, 192 / 64, BATCH), 256, 0, stream>>>(
        xpool, (size_t)G * CH, WvT, 0, CH, lvT, (size_t)192 * G, G, 0, nullptr);

    // ---- attention ----
    hi_attn<<<dim3(BATCH * G), 128, 0, stream>>>(tokf, hi_ao);
    lo_attn<<<dim3(NTOK / 64, HEADS, BATCH), 256, 0, stream>>>(tokf, lkK, lvT, lo_ao);

    // ---- projections (f32 out, transposed layout [j][n], + bias) ----
    gemm_rk<true><<<dim3(NTOK / 64, 192 / 64, BATCH), 256, 0, stream>>>(
        hi_ao, (size_t)NTOK * 192, WhpT, 0, 192, out, (size_t)CH * NTOK, NTOK, 0, bh_proj);
    gemm_rk<true><<<dim3(NTOK / 64, 192 / 64, BATCH), 256, 0, stream>>>(
        lo_ao, (size_t)NTOK * 192, WlpT, 0, 192, out, (size_t)CH * NTOK, NTOK, 192, bl_proj);
}